// Round 5
// baseline (232.855 us; speedup 1.0000x reference)
//
#include <hip/hip_runtime.h>

#define TILE  256
#define CIN   32
#define COUT  64
#define LSIZE 16384
#define NBITS 14

typedef float f32x4 __attribute__((ext_vector_type(4)));

__device__ __forceinline__ f32x4 splat4(float s) {
    f32x4 v = {s, s, s, s};
    return v;
}

__global__ __launch_bounds__(256, 5)
void hamming_fused(const float* __restrict__ x,
                   const float* __restrict__ w_self,
                   const float* __restrict__ w_bits,
                   const float* __restrict__ mix_w,
                   const float* __restrict__ mix_b,
                   float* __restrict__ out)
{
    __shared__ float xs[CIN][TILE];     // 32 KiB ONLY: x tile, then y (linear)

    const int tid  = threadIdx.x;       // 0..255
    const int lane = tid & 63;
    const int wv   = tid >> 6;          // wave id 0..3

    // ---- XCD-aware remap: each XCD owns 4 whole batches; a batch's 2 MiB
    // x-slab stays resident in that XCD's 4 MiB L2 for the cross-tile taps.
    const int d    = blockIdx.x;        // 0..2047
    const int xcd  = d & 7;
    const int j    = d >> 3;
    const int b    = xcd * 4 + (j >> 6);
    const int tile = j & 63;
    const int base = tile * TILE;
    const float* xb = x + (size_t)b * CIN * LSIZE;

    // ---- stage x tile via async global->LDS (16B/lane, wave-uniform base) ----
    #pragma unroll
    for (int i = 0; i < 8; ++i) {
        const int r = wv + i * 4;                        // wave-uniform row
        const float* src = xb + (size_t)r * LSIZE + base + lane * 4;
        __builtin_amdgcn_global_load_lds(
            (const __attribute__((address_space(1))) void*)src,
            (__attribute__((address_space(3))) void*)&xs[r][lane * 4],
            16, 0, 0);
    }

    const float ws = w_self[0];
    float wb[NBITS];
    #pragma unroll
    for (int k = 0; k < NBITS; ++k) wb[k] = w_bits[k];

    __syncthreads();                    // drains vmcnt: xs ready

    // ---- stage 1: hypercube stencil, float4 form (proven in round 3).
    // wave wv owns channels 8wv..8wv+7; each lane owns 4 consecutive columns.
    const int c0ch = wv * 8;
    const int colb = lane * 4;

    f32x4 yv[8];
    #pragma unroll
    for (int cc = 0; cc < 8; cc += 2) {
        // prefetch 12 cross-tile dwordx4 (bits 8..13, L2-resident after remap)
        f32x4 pf[2][6];
        #pragma unroll
        for (int u = 0; u < 2; ++u) {
            const float* xr = xb + (size_t)(c0ch + cc + u) * LSIZE;
            #pragma unroll
            for (int kk = 0; kk < 6; ++kk)
                pf[u][kk] = *(const f32x4*)(xr + ((base ^ (TILE << kk)) + colb));
        }
        #pragma unroll
        for (int u = 0; u < 2; ++u) {
            const int c = c0ch + cc + u;
            const f32x4 s = *(const f32x4*)&xs[c][colb];
            f32x4 a = s * ws;
            // bits 0,1: neighbors inside the float4 -> register permutes
            a.x += wb[0] * s.y; a.y += wb[0] * s.x; a.z += wb[0] * s.w; a.w += wb[0] * s.z;
            a.x += wb[1] * s.z; a.y += wb[1] * s.w; a.z += wb[1] * s.x; a.w += wb[1] * s.y;
            // bits 2..7: in-tile, float4-contiguous under XOR
            #pragma unroll
            for (int k = 2; k < 8; ++k) {
                const f32x4 t = *(const f32x4*)&xs[c][colb ^ (1 << k)];
                a += wb[k] * t;
            }
            #pragma unroll
            for (int kk = 0; kk < 6; ++kk)
                a += wb[8 + kk] * pf[u][kk];
            yv[cc + u] = a * (1.0f / 15.0f);
        }
    }
    __syncthreads();                    // all xs reads done before overwrite

    // ---- write y back LINEAR ----
    #pragma unroll
    for (int cc = 0; cc < 8; ++cc)
        *(f32x4*)&xs[c0ch + cc][colb] = yv[cc];
    __syncthreads();

    // ---- stage 2: channel mix, c-chunked; w straight from global (L1-hot,
    // wave-uniform broadcast float4) -> no LDS staging, no bank conflicts.
    const int tx  = tid & 63;
    const int ty  = tid >> 6;
    const int cb2 = tx << 2;            // 4 consecutive columns
    const int o0  = ty * 16;            // 16 outputs per thread

    f32x4 acc[16];
    #pragma unroll
    for (int q = 0; q < 4; ++q) {
        const f32x4 b4 = *(const f32x4*)(mix_b + o0 + q * 4);
        acc[q * 4 + 0] = splat4(b4.x);
        acc[q * 4 + 1] = splat4(b4.y);
        acc[q * 4 + 2] = splat4(b4.z);
        acc[q * 4 + 3] = splat4(b4.w);
    }

    #pragma unroll 1
    for (int c0 = 0; c0 < CIN; c0 += 4) {
        const f32x4 y0 = *(const f32x4*)&xs[c0 + 0][cb2];
        const f32x4 y1 = *(const f32x4*)&xs[c0 + 1][cb2];
        const f32x4 y2 = *(const f32x4*)&xs[c0 + 2][cb2];
        const f32x4 y3 = *(const f32x4*)&xs[c0 + 3][cb2];
        const float* wp = mix_w + o0 * CIN + c0;
        #pragma unroll
        for (int jj = 0; jj < 16; ++jj) {
            const f32x4 w4 = *(const f32x4*)(wp + jj * CIN);  // wave-uniform
            acc[jj] += w4.x * y0;
            acc[jj] += w4.y * y1;
            acc[jj] += w4.z * y2;
            acc[jj] += w4.w * y3;
        }
    }

    // ---- store: coalesced float4, non-temporal ----
    float* ob = out + (size_t)b * COUT * LSIZE;
    #pragma unroll
    for (int jj = 0; jj < 16; ++jj) {
        f32x4* p = (f32x4*)(ob + (size_t)(o0 + jj) * LSIZE + base + cb2);
        __builtin_nontemporal_store(acc[jj], p);
    }
}

extern "C" void kernel_launch(void* const* d_in, const int* in_sizes, int n_in,
                              void* d_out, int out_size, void* d_ws, size_t ws_size,
                              hipStream_t stream) {
    const float* x      = (const float*)d_in[0];
    const float* w_self = (const float*)d_in[1];
    const float* w_bits = (const float*)d_in[2];
    const float* mix_w  = (const float*)d_in[3];
    const float* mix_b  = (const float*)d_in[4];
    float* out = (float*)d_out;

    hamming_fused<<<dim3(2048), 256, 0, stream>>>(x, w_self, w_bits, mix_w, mix_b, out);
}

// Round 6
// 216.111 us; speedup vs baseline: 1.0775x; 1.0775x over previous
//
#include <hip/hip_runtime.h>

#define TILE  256
#define CIN   32
#define COUT  64
#define LSIZE 16384
#define NBITS 14

typedef float f32x4 __attribute__((ext_vector_type(4)));

__device__ __forceinline__ f32x4 splat4(float s) {
    f32x4 v = {s, s, s, s};
    return v;
}

__global__ __launch_bounds__(256, 4)
void hamming_fused(const float* __restrict__ x,
                   const float* __restrict__ w_self,
                   const float* __restrict__ w_bits,
                   const float* __restrict__ mix_w,
                   const float* __restrict__ mix_b,
                   float* __restrict__ out)
{
    __shared__ float xs[CIN][TILE];     // 32 KiB: x tile, then y (in place, per-wave rows)
    __shared__ float mwl[COUT * CIN];   // 8 KiB: mix_w VERBATIM [o][c] -> broadcast reads

    const int tid  = threadIdx.x;       // 0..255
    const int lane = tid & 63;
    const int wv   = tid >> 6;          // wave id 0..3

    // ---- XCD-aware remap: each XCD owns 4 whole batches; a batch's 2 MiB
    // x-slab stays resident in that XCD's 4 MiB L2 for the cross-tile taps.
    const int d    = blockIdx.x;        // 0..2047
    const int xcd  = d & 7;
    const int j    = d >> 3;
    const int b    = xcd * 4 + (j >> 6);
    const int tile = j & 63;
    const int base = tile * TILE;
    const float* xb = x + (size_t)b * CIN * LSIZE;

    // wave wv owns channels 8wv..8wv+7; each lane owns 4 consecutive columns.
    const int c0ch = wv * 8;
    const int colb = lane * 4;

    // ---- prologue: issue cross-tile taps for channels 0,1 of this wave NOW.
    // They read global x only (independent of LDS staging) -> latency hides
    // under the 32 KiB DMA + barrier. Ring pf[3][6], fully unrolled indices.
    f32x4 pf[3][6];
    #pragma unroll
    for (int u = 0; u < 2; ++u) {
        const float* xr = xb + (size_t)(c0ch + u) * LSIZE;
        #pragma unroll
        for (int kk = 0; kk < 6; ++kk)
            pf[u][kk] = *(const f32x4*)(xr + ((base ^ (TILE << kk)) + colb));
    }

    // ---- stage x tile via async global->LDS (16B/lane, wave-uniform base) ----
    #pragma unroll
    for (int i = 0; i < 8; ++i) {
        const int r = wv + i * 4;                        // wave-uniform row
        const float* src = xb + (size_t)r * LSIZE + base + lane * 4;
        __builtin_amdgcn_global_load_lds(
            (const __attribute__((address_space(1))) void*)src,
            (__attribute__((address_space(3))) void*)&xs[r][lane * 4],
            16, 0, 0);
    }
    // ---- stage mix_w verbatim via async global->LDS (conflict-free) ----
    #pragma unroll
    for (int i = 0; i < 2; ++i) {
        const int q = tid + i * 256;                     // float4 index
        const float* src = mix_w + q * 4;
        __builtin_amdgcn_global_load_lds(
            (const __attribute__((address_space(1))) void*)src,
            (__attribute__((address_space(3))) void*)&mwl[q * 4],
            16, 0, 0);
    }

    const float ws = w_self[0];
    float wb[NBITS];
    #pragma unroll
    for (int k = 0; k < NBITS; ++k) wb[k] = w_bits[k];

    __syncthreads();                    // drains vmcnt: xs, mwl (and taps) ready

    // ---- stage 1: hypercube stencil, software-pipelined taps (depth 2).
    // No barrier needed before y write-back: each wave touches ONLY its own
    // 8 rows, and within-wave DS ops are in-order (reads precede the write).
    #pragma unroll
    for (int cc = 0; cc < 8; ++cc) {
        if (cc + 2 < 8) {               // issue taps 2 channels ahead
            const float* xr = xb + (size_t)(c0ch + cc + 2) * LSIZE;
            #pragma unroll
            for (int kk = 0; kk < 6; ++kk)
                pf[(cc + 2) % 3][kk] =
                    *(const f32x4*)(xr + ((base ^ (TILE << kk)) + colb));
        }
        const int c = c0ch + cc;
        const f32x4 s = *(const f32x4*)&xs[c][colb];
        f32x4 a = s * ws;
        // bits 0,1: neighbors inside the float4 -> register permutes
        a.x += wb[0] * s.y; a.y += wb[0] * s.x; a.z += wb[0] * s.w; a.w += wb[0] * s.z;
        a.x += wb[1] * s.z; a.y += wb[1] * s.w; a.z += wb[1] * s.x; a.w += wb[1] * s.y;
        // bits 2..7: in-tile, float4-contiguous under XOR
        #pragma unroll
        for (int k = 2; k < 8; ++k) {
            const f32x4 t = *(const f32x4*)&xs[c][colb ^ (1 << k)];
            a += wb[k] * t;
        }
        // bits 8..13: the prefetched cross-tile taps (issued >=2 iters ago)
        #pragma unroll
        for (int kk = 0; kk < 6; ++kk)
            a += wb[8 + kk] * pf[cc % 3][kk];
        a *= (1.0f / 15.0f);
        *(f32x4*)&xs[c][colb] = a;      // in-place y write, own row
    }
    __syncthreads();                    // single rendezvous before cross-wave reads

    // ---- stage 2: channel mix; w via wave-uniform LDS broadcast (mwl linear),
    // y via per-lane b128 reads. unroll 2 for cross-chunk ILP.
    const int tx  = tid & 63;
    const int ty  = tid >> 6;
    const int cb2 = tx << 2;            // 4 consecutive columns
    const int o0  = ty * 16;            // 16 outputs per thread

    f32x4 acc[16];
    #pragma unroll
    for (int q = 0; q < 4; ++q) {
        const f32x4 b4 = *(const f32x4*)(mix_b + o0 + q * 4);
        acc[q * 4 + 0] = splat4(b4.x);
        acc[q * 4 + 1] = splat4(b4.y);
        acc[q * 4 + 2] = splat4(b4.z);
        acc[q * 4 + 3] = splat4(b4.w);
    }

    #pragma unroll 2
    for (int c0 = 0; c0 < CIN; c0 += 4) {
        const f32x4 y0 = *(const f32x4*)&xs[c0 + 0][cb2];
        const f32x4 y1 = *(const f32x4*)&xs[c0 + 1][cb2];
        const f32x4 y2 = *(const f32x4*)&xs[c0 + 2][cb2];
        const f32x4 y3 = *(const f32x4*)&xs[c0 + 3][cb2];
        #pragma unroll
        for (int jj = 0; jj < 16; ++jj) {
            const f32x4 w4 = *(const f32x4*)&mwl[(o0 + jj) * CIN + c0]; // broadcast
            acc[jj] += w4.x * y0;
            acc[jj] += w4.y * y1;
            acc[jj] += w4.z * y2;
            acc[jj] += w4.w * y3;
        }
    }

    // ---- store: coalesced float4, non-temporal ----
    float* ob = out + (size_t)b * COUT * LSIZE;
    #pragma unroll
    for (int jj = 0; jj < 16; ++jj) {
        f32x4* p = (f32x4*)(ob + (size_t)(o0 + jj) * LSIZE + base + cb2);
        __builtin_nontemporal_store(acc[jj], p);
    }
}

extern "C" void kernel_launch(void* const* d_in, const int* in_sizes, int n_in,
                              void* d_out, int out_size, void* d_ws, size_t ws_size,
                              hipStream_t stream) {
    const float* x      = (const float*)d_in[0];
    const float* w_self = (const float*)d_in[1];
    const float* w_bits = (const float*)d_in[2];
    const float* mix_w  = (const float*)d_in[3];
    const float* mix_b  = (const float*)d_in[4];
    float* out = (float*)d_out;

    hamming_fused<<<dim3(2048), 256, 0, stream>>>(x, w_self, w_bits, mix_w, mix_b, out);
}

// Round 7
// 207.572 us; speedup vs baseline: 1.1218x; 1.0411x over previous
//
#include <hip/hip_runtime.h>

#define TILE  256
#define CIN   32
#define COUT  64
#define LSIZE 16384
#define NBITS 14

typedef float f32x4 __attribute__((ext_vector_type(4)));

__device__ __forceinline__ f32x4 splat4(float s) {
    f32x4 v = {s, s, s, s};
    return v;
}

__global__ __launch_bounds__(256, 4)
void hamming_fused(const float* __restrict__ x,
                   const float* __restrict__ w_self,
                   const float* __restrict__ w_bits,
                   const float* __restrict__ mix_w,
                   const float* __restrict__ mix_b,
                   float* __restrict__ out)
{
    __shared__ float xs[CIN][TILE];     // 32 KiB: x tile, then y (in place, per-wave rows)
    __shared__ float mwl[COUT * CIN];   // 8 KiB: mix_w VERBATIM [o][c] -> broadcast reads

    const int tid  = threadIdx.x;       // 0..255
    const int lane = tid & 63;
    const int wv   = tid >> 6;          // wave id 0..3

    // ---- XCD-aware remap: each XCD owns 4 whole batches; a batch's 2 MiB
    // x-slab stays resident in that XCD's 4 MiB L2 for the cross-tile taps.
    const int d    = blockIdx.x;        // 0..2047
    const int xcd  = d & 7;
    const int j    = d >> 3;
    const int b    = xcd * 4 + (j >> 6);
    const int tile = j & 63;
    const int base = tile * TILE;
    const float* xb = x + (size_t)b * CIN * LSIZE;

    // wave wv owns channels 8wv..8wv+7; each lane owns 4 consecutive columns.
    const int c0ch = wv * 8;
    const int colb = lane * 4;

    // ---- stage x tile + mix_w via async global->LDS (issue FIRST: longest DMA) ----
    #pragma unroll
    for (int i = 0; i < 8; ++i) {
        const int r = wv + i * 4;                        // wave-uniform row
        const float* src = xb + (size_t)r * LSIZE + base + lane * 4;
        __builtin_amdgcn_global_load_lds(
            (const __attribute__((address_space(1))) void*)src,
            (__attribute__((address_space(3))) void*)&xs[r][lane * 4],
            16, 0, 0);
    }
    #pragma unroll
    for (int i = 0; i < 2; ++i) {
        const int q = tid + i * 256;                     // float4 index
        const float* src = mix_w + q * 4;
        __builtin_amdgcn_global_load_lds(
            (const __attribute__((address_space(1))) void*)src,
            (__attribute__((address_space(3))) void*)&mwl[q * 4],
            16, 0, 0);
    }

    // ---- tap issue / compute helpers (all indices compile-time constant) ----
    const float ws = w_self[0];
    float wb[NBITS];
    #pragma unroll
    for (int k = 0; k < NBITS; ++k) wb[k] = w_bits[k];

    auto issue_taps = [&](int ch, f32x4 (&pf)[6]) {
        const float* xr = xb + (size_t)(c0ch + ch) * LSIZE;
        #pragma unroll
        for (int kk = 0; kk < 6; ++kk)
            pf[kk] = *(const f32x4*)(xr + ((base ^ (TILE << kk)) + colb));
    };
    auto compute_ch = [&](int ch, const f32x4 (&pf)[6]) {
        const int c = c0ch + ch;
        const f32x4 s = *(const f32x4*)&xs[c][colb];
        f32x4 a = s * ws;
        // bits 0,1: neighbors inside the float4 -> register permutes
        a.x += wb[0] * s.y; a.y += wb[0] * s.x; a.z += wb[0] * s.w; a.w += wb[0] * s.z;
        a.x += wb[1] * s.z; a.y += wb[1] * s.w; a.z += wb[1] * s.x; a.w += wb[1] * s.y;
        // bits 2..7: in-tile, float4-contiguous under XOR
        #pragma unroll
        for (int k = 2; k < 8; ++k) {
            const f32x4 t = *(const f32x4*)&xs[c][colb ^ (1 << k)];
            a += wb[k] * t;
        }
        // bits 8..13: prefetched cross-tile taps
        #pragma unroll
        for (int kk = 0; kk < 6; ++kk)
            a += wb[8 + kk] * pf[kk];
        a *= (1.0f / 15.0f);
        *(f32x4*)&xs[c][colb] = a;      // in-place y write, own row (within-wave in-order)
    };

    // ---- enforced-issue tap pipeline: 2-channel batches, ping-pong A/B.
    // Batch(ch0,1) rides under the staging barrier's vmcnt(0) drain (free cover);
    // every later batch is covered by one 2-channel compute phase. sched_barrier(0)
    // fences stop the compiler from sinking loads back next to their uses
    // (round-6 failure mode: VGPR=64 proved the source-level pipeline was deleted).
    f32x4 pA0[6], pA1[6], pB0[6], pB1[6];

    issue_taps(0, pA0); issue_taps(1, pA1);
    __builtin_amdgcn_sched_barrier(0);

    __syncthreads();                    // drains vmcnt: xs, mwl AND batch A ready

    issue_taps(2, pB0); issue_taps(3, pB1);
    __builtin_amdgcn_sched_barrier(0);
    compute_ch(0, pA0); compute_ch(1, pA1);
    __builtin_amdgcn_sched_barrier(0);

    issue_taps(4, pA0); issue_taps(5, pA1);
    __builtin_amdgcn_sched_barrier(0);
    compute_ch(2, pB0); compute_ch(3, pB1);
    __builtin_amdgcn_sched_barrier(0);

    issue_taps(6, pB0); issue_taps(7, pB1);
    __builtin_amdgcn_sched_barrier(0);
    compute_ch(4, pA0); compute_ch(5, pA1);
    __builtin_amdgcn_sched_barrier(0);

    compute_ch(6, pB0); compute_ch(7, pB1);

    __syncthreads();                    // single rendezvous before cross-wave reads

    // ---- stage 2: channel mix; w via wave-uniform LDS broadcast (mwl linear),
    // y via per-lane b128 reads. unroll 2 for cross-chunk ILP.
    const int tx  = tid & 63;
    const int ty  = tid >> 6;
    const int cb2 = tx << 2;            // 4 consecutive columns
    const int o0  = ty * 16;            // 16 outputs per thread

    f32x4 acc[16];
    #pragma unroll
    for (int q = 0; q < 4; ++q) {
        const f32x4 b4 = *(const f32x4*)(mix_b + o0 + q * 4);
        acc[q * 4 + 0] = splat4(b4.x);
        acc[q * 4 + 1] = splat4(b4.y);
        acc[q * 4 + 2] = splat4(b4.z);
        acc[q * 4 + 3] = splat4(b4.w);
    }

    #pragma unroll 2
    for (int c0 = 0; c0 < CIN; c0 += 4) {
        const f32x4 y0 = *(const f32x4*)&xs[c0 + 0][cb2];
        const f32x4 y1 = *(const f32x4*)&xs[c0 + 1][cb2];
        const f32x4 y2 = *(const f32x4*)&xs[c0 + 2][cb2];
        const f32x4 y3 = *(const f32x4*)&xs[c0 + 3][cb2];
        #pragma unroll
        for (int jj = 0; jj < 16; ++jj) {
            const f32x4 w4 = *(const f32x4*)&mwl[(o0 + jj) * CIN + c0]; // broadcast
            acc[jj] += w4.x * y0;
            acc[jj] += w4.y * y1;
            acc[jj] += w4.z * y2;
            acc[jj] += w4.w * y3;
        }
    }

    // ---- store: coalesced float4, non-temporal ----
    float* ob = out + (size_t)b * COUT * LSIZE;
    #pragma unroll
    for (int jj = 0; jj < 16; ++jj) {
        f32x4* p = (f32x4*)(ob + (size_t)(o0 + jj) * LSIZE + base + cb2);
        __builtin_nontemporal_store(acc[jj], p);
    }
}

extern "C" void kernel_launch(void* const* d_in, const int* in_sizes, int n_in,
                              void* d_out, int out_size, void* d_ws, size_t ws_size,
                              hipStream_t stream) {
    const float* x      = (const float*)d_in[0];
    const float* w_self = (const float*)d_in[1];
    const float* w_bits = (const float*)d_in[2];
    const float* mix_w  = (const float*)d_in[3];
    const float* mix_b  = (const float*)d_in[4];
    float* out = (float*)d_out;

    hamming_fused<<<dim3(2048), 256, 0, stream>>>(x, w_self, w_bits, mix_w, mix_b, out);
}